// Round 5
// baseline (490.543 us; speedup 1.0000x reference)
//
#include <hip/hip_runtime.h>

// MoE fp32: route top-2 -> gather -> bf16 MFMA GEMMs.
// R5: R4 + fix router xb store (was writing only 16 of 32 bytes per lane).
// Vectorized B staging (full-row float2 wave loads), distance-2 register
// prefetch, 16B-aligned conflict-free LDS (LP=40), gemm2 split-K=8.

typedef __bf16 bf16;
typedef __bf16 bf16x8 __attribute__((ext_vector_type(8)));
typedef float floatx4 __attribute__((ext_vector_type(4)));

#define T_TOK 1024
#define HID 1024
#define FFN 4096
#define NEXP 8
#define BM 128
#define BN 128
#define BK 32
#define LP 40    // bf16 row stride: 80 B -> every row 16B-aligned, b128 R/W conflict-free
#define KS2 8    // gemm2 split-K ways

// ---------------- Router (+ x -> bf16) ----------------
__global__ void router_k(const float* __restrict__ x, const float* __restrict__ gw,
                         const float* __restrict__ gb, int* __restrict__ cnt,
                         int* __restrict__ elist, float* __restrict__ ewt,
                         bf16* __restrict__ xb) {
  int wave = threadIdx.x >> 6;
  int lane = threadIdx.x & 63;
  int t = blockIdx.x * 4 + wave;
  const float* xr = x + (size_t)t * HID + lane * 16;
  float4 xv[4];
#pragma unroll
  for (int c = 0; c < 4; c++) xv[c] = ((const float4*)xr)[c];
  // write bf16 row: 16 elems = 32 B per lane -> TWO uint4 stores
  bf16 tv[16];
#pragma unroll
  for (int c = 0; c < 4; c++) {
    tv[c * 4 + 0] = (bf16)xv[c].x; tv[c * 4 + 1] = (bf16)xv[c].y;
    tv[c * 4 + 2] = (bf16)xv[c].z; tv[c * 4 + 3] = (bf16)xv[c].w;
  }
  *(uint4*)&xb[(size_t)t * HID + lane * 16]     = ((uint4*)tv)[0];
  *(uint4*)&xb[(size_t)t * HID + lane * 16 + 8] = ((uint4*)tv)[1];

  float logits[NEXP];
#pragma unroll
  for (int e = 0; e < NEXP; e++) {
    const float* g = gw + (size_t)e * HID + lane * 16;
    float s = 0.f;
#pragma unroll
    for (int c = 0; c < 4; c++) {
      float4 gv = ((const float4*)g)[c];
      s += xv[c].x * gv.x + xv[c].y * gv.y + xv[c].z * gv.z + xv[c].w * gv.w;
    }
#pragma unroll
    for (int off = 32; off; off >>= 1) s += __shfl_xor(s, off, 64);
    logits[e] = s + gb[e];
  }
  int i0 = 0; float l0 = logits[0];
#pragma unroll
  for (int e = 1; e < NEXP; e++) if (logits[e] > l0) { l0 = logits[e]; i0 = e; }
  int i1 = -1; float l1 = -3.0e38f;
#pragma unroll
  for (int e = 0; e < NEXP; e++) if (e != i0 && logits[e] > l1) { l1 = logits[e]; i1 = e; }
  if (lane == 0) {
    float w0 = 1.f / (1.f + expf(l1 - l0));
    float w1 = 1.f - w0;
    int p0 = atomicAdd(cnt + i0, 1);
    elist[i0 * T_TOK + p0] = t * 2 + 0; ewt[i0 * T_TOK + p0] = w0;
    int p1 = atomicAdd(cnt + i1, 1);
    elist[i1 * T_TOK + p1] = t * 2 + 1; ewt[i1 * T_TOK + p1] = w1;
  }
}

// ---------------- GEMM1: h = gelu(Xg @ w1 + b1) ----------------
__global__ __launch_bounds__(256)
void gemm1_k(const bf16* __restrict__ xb, const float* __restrict__ w1,
             const float* __restrict__ b1, const int* __restrict__ cnt,
             const int* __restrict__ elist, bf16* __restrict__ hbuf) {
  int e = blockIdx.z;
  int c = cnt[e];
  int m0 = blockIdx.y * BM;
  if (m0 >= c) return;
  int n0 = blockIdx.x * BN;

  __shared__ __align__(16) bf16 As[BM][LP];
  __shared__ __align__(16) bf16 Bs[BN][LP];

  int tid = threadIdx.x;
  int ar = tid >> 1, ah = (tid & 1) * 16;
  int ra = m0 + ar; if (ra >= c) ra = c - 1;
  const bf16* abase = xb + (size_t)(elist[e * T_TOK + ra] >> 1) * HID + ah;
  int bn2 = (tid & 63) * 2;       // 2 consecutive n per thread
  int bq8 = (tid >> 6) * 8;       // wave-uniform k-block
  const float* bbase = w1 + (size_t)e * HID * FFN + (size_t)bq8 * FFN + n0 + bn2;

  uint4 pa[2][2];
  float2 pb[2][8];

#define G1LOAD(s, kt) do { \
    const bf16* ap = abase + (kt) * BK; \
    pa[s][0] = *(const uint4*)ap; \
    pa[s][1] = *(const uint4*)(ap + 8); \
    const float* bp = bbase + (size_t)(kt) * BK * FFN; \
    _Pragma("unroll") for (int j = 0; j < 8; j++) \
      pb[s][j] = *(const float2*)(bp + (size_t)j * FFN); \
  } while (0)

  G1LOAD(0, 0);
  G1LOAD(1, 1);

  floatx4 acc[4][4] = {};
  int ln = tid & 63, wv = tid >> 6;
  int fm = ln & 15, quad = ln >> 4;
  int wm = (wv & 1) * 64, wn = (wv >> 1) * 64;
  const int NT = HID / BK;  // 32

#define G1STEP(s, t) do { \
    bf16 c0[8], c1[8]; \
    _Pragma("unroll") for (int j = 0; j < 8; j++) { \
      c0[j] = (bf16)pb[s][j].x; c1[j] = (bf16)pb[s][j].y; } \
    uint4 wa0 = pa[s][0], wa1 = pa[s][1]; \
    __syncthreads(); \
    *(uint4*)&As[ar][ah]     = wa0; \
    *(uint4*)&As[ar][ah + 8] = wa1; \
    *(bf16x8*)&Bs[bn2][bq8]     = *(bf16x8*)c0; \
    *(bf16x8*)&Bs[bn2 + 1][bq8] = *(bf16x8*)c1; \
    if ((t) + 2 < NT) G1LOAD(s, (t) + 2); \
    __syncthreads(); \
    bf16x8 af[4], bfr[4]; \
    _Pragma("unroll") for (int i = 0; i < 4; i++) \
      af[i] = *(const bf16x8*)&As[wm + i * 16 + fm][quad * 8]; \
    _Pragma("unroll") for (int j = 0; j < 4; j++) \
      bfr[j] = *(const bf16x8*)&Bs[wn + j * 16 + fm][quad * 8]; \
    _Pragma("unroll") for (int i = 0; i < 4; i++) \
      _Pragma("unroll") for (int j = 0; j < 4; j++) \
        acc[i][j] = __builtin_amdgcn_mfma_f32_16x16x32_bf16(af[i], bfr[j], acc[i][j], 0, 0, 0); \
  } while (0)

  for (int tt = 0; tt < NT; tt += 2) { G1STEP(0, tt); G1STEP(1, tt + 1); }

  const float* b1e = b1 + (size_t)e * FFN;
#pragma unroll
  for (int i = 0; i < 4; i++) {
    int rb = m0 + wm + i * 16 + quad * 4;
#pragma unroll
    for (int j = 0; j < 4; j++) {
      int col = n0 + wn + j * 16 + fm;
      float bias = b1e[col];
#pragma unroll
      for (int r = 0; r < 4; r++) {
        int row = rb + r;
        if (row < c) {
          int slot = elist[e * T_TOK + row];
          float v = acc[i][j][r] + bias;
          float g = 0.5f * v * (1.f + erff(v * 0.70710678118654752f));
          hbuf[(size_t)slot * FFN + col] = (bf16)g;
        }
      }
    }
  }
}

// ---------------- GEMM2 split-K=8: part[ks][slot] = wt*(h @ w2 + b2?) ----------------
__global__ __launch_bounds__(256)
void gemm2_k(const bf16* __restrict__ hbuf, const float* __restrict__ w2,
             const float* __restrict__ b2, const int* __restrict__ cnt,
             const int* __restrict__ elist, const float* __restrict__ ewt,
             float* __restrict__ part) {
  int e = blockIdx.z & 7;
  int ks = blockIdx.z >> 3;
  int c = cnt[e];
  int m0 = blockIdx.y * BM;
  if (m0 >= c) return;
  int n0 = blockIdx.x * BN;
  int kbeg = ks * (FFN / KS2);

  __shared__ __align__(16) bf16 As[BM][LP];
  __shared__ __align__(16) bf16 Bs[BN][LP];

  int tid = threadIdx.x;
  int ar = tid >> 1, ah = (tid & 1) * 16;
  int ra = m0 + ar; if (ra >= c) ra = c - 1;
  const bf16* abase = hbuf + (size_t)elist[e * T_TOK + ra] * FFN + kbeg + ah;
  int bn2 = (tid & 63) * 2;
  int bq8 = (tid >> 6) * 8;
  const float* bbase = w2 + (size_t)e * FFN * HID + (size_t)(kbeg + bq8) * HID + n0 + bn2;

  uint4 pa[2][2];
  float2 pb[2][8];

#define G2LOAD(s, kt) do { \
    const bf16* ap = abase + (kt) * BK; \
    pa[s][0] = *(const uint4*)ap; \
    pa[s][1] = *(const uint4*)(ap + 8); \
    const float* bp = bbase + (size_t)(kt) * BK * HID; \
    _Pragma("unroll") for (int j = 0; j < 8; j++) \
      pb[s][j] = *(const float2*)(bp + (size_t)j * HID); \
  } while (0)

  G2LOAD(0, 0);
  G2LOAD(1, 1);

  floatx4 acc[4][4] = {};
  int ln = tid & 63, wv = tid >> 6;
  int fm = ln & 15, quad = ln >> 4;
  int wm = (wv & 1) * 64, wn = (wv >> 1) * 64;
  const int NT = (FFN / KS2) / BK;  // 16

#define G2STEP(s, t) do { \
    bf16 c0[8], c1[8]; \
    _Pragma("unroll") for (int j = 0; j < 8; j++) { \
      c0[j] = (bf16)pb[s][j].x; c1[j] = (bf16)pb[s][j].y; } \
    uint4 wa0 = pa[s][0], wa1 = pa[s][1]; \
    __syncthreads(); \
    *(uint4*)&As[ar][ah]     = wa0; \
    *(uint4*)&As[ar][ah + 8] = wa1; \
    *(bf16x8*)&Bs[bn2][bq8]     = *(bf16x8*)c0; \
    *(bf16x8*)&Bs[bn2 + 1][bq8] = *(bf16x8*)c1; \
    if ((t) + 2 < NT) G2LOAD(s, (t) + 2); \
    __syncthreads(); \
    bf16x8 af[4], bfr[4]; \
    _Pragma("unroll") for (int i = 0; i < 4; i++) \
      af[i] = *(const bf16x8*)&As[wm + i * 16 + fm][quad * 8]; \
    _Pragma("unroll") for (int j = 0; j < 4; j++) \
      bfr[j] = *(const bf16x8*)&Bs[wn + j * 16 + fm][quad * 8]; \
    _Pragma("unroll") for (int i = 0; i < 4; i++) \
      _Pragma("unroll") for (int j = 0; j < 4; j++) \
        acc[i][j] = __builtin_amdgcn_mfma_f32_16x16x32_bf16(af[i], bfr[j], acc[i][j], 0, 0, 0); \
  } while (0)

  for (int tt = 0; tt < NT; tt += 2) { G2STEP(0, tt); G2STEP(1, tt + 1); }

  const float* b2e = b2 + (size_t)e * HID;
#pragma unroll
  for (int i = 0; i < 4; i++) {
    int rb = m0 + wm + i * 16 + quad * 4;
#pragma unroll
    for (int j = 0; j < 4; j++) {
      int col = n0 + wn + j * 16 + fm;
      float bias = (ks == 0) ? b2e[col] : 0.f;
#pragma unroll
      for (int r = 0; r < 4; r++) {
        int row = rb + r;
        if (row < c) {
          int slot = elist[e * T_TOK + row];
          float w = ewt[e * T_TOK + row];
          part[((size_t)ks * (2 * T_TOK) + slot) * HID + col] = w * (acc[i][j][r] + bias);
        }
      }
    }
  }
}

// ---------------- Combine: out[t] = sum over KS2 x 2 slots ----------------
__global__ void combine_k(const float* __restrict__ part, float* __restrict__ out) {
  int i = blockIdx.x * 256 + threadIdx.x;
  int t = i >> 8;
  int h4 = (i & 255) * 4;
  float4 s = {0.f, 0.f, 0.f, 0.f};
#pragma unroll
  for (int ks = 0; ks < KS2; ks++)
#pragma unroll
    for (int sl = 0; sl < 2; sl++) {
      float4 v = *(const float4*)&part[((size_t)ks * (2 * T_TOK) + t * 2 + sl) * HID + h4];
      s.x += v.x; s.y += v.y; s.z += v.z; s.w += v.w;
    }
  *(float4*)&out[(size_t)t * HID + h4] = s;
}

extern "C" void kernel_launch(void* const* d_in, const int* in_sizes, int n_in,
                              void* d_out, int out_size, void* d_ws, size_t ws_size,
                              hipStream_t stream) {
  const float* x  = (const float*)d_in[0];
  const float* gw = (const float*)d_in[1];
  const float* gb = (const float*)d_in[2];
  const float* w1 = (const float*)d_in[3];
  const float* b1 = (const float*)d_in[4];
  const float* w2 = (const float*)d_in[5];
  const float* b2 = (const float*)d_in[6];
  float* out = (float*)d_out;

  char* ws = (char*)d_ws;
  int*   cnt   = (int*)ws;                                   // 32 B
  int*   elist = (int*)(ws + 1024);                          // 32 KB
  float* ewt   = (float*)(ws + 1024 + 32768);                // 32 KB
  bf16*  xb    = (bf16*)(ws + (1 << 16));                    // 2 MB
  bf16*  hbuf  = (bf16*)(ws + ((size_t)4 << 20));            // 16.8 MB
  float* part  = (float*)(ws + ((size_t)24 << 20));          // 67 MB (KS2=8)

  hipMemsetAsync(cnt, 0, 32, stream);
  router_k<<<T_TOK / 4, 256, 0, stream>>>(x, gw, gb, cnt, elist, ewt, xb);
  gemm1_k<<<dim3(FFN / BN, 8, NEXP), 256, 0, stream>>>(xb, w1, b1, cnt, elist, hbuf);
  gemm2_k<<<dim3(HID / BN, 8, NEXP * KS2), 256, 0, stream>>>(hbuf, w2, b2, cnt, elist, ewt, part);
  combine_k<<<(T_TOK * HID / 4) / 256, 256, 0, stream>>>(part, out);
}